// Round 2
// baseline (1775.216 us; speedup 1.0000x reference)
//
#include <hip/hip_runtime.h>
#include <math.h>

constexpr int NROWS = 32768;   // B
constexpr int DIMC  = 256;     // D
constexpr int KC    = 4096;    // K

// ---------------------------------------------------------------------------
// Kernel A: anorm[row] = fp32( sum_f64 z^2 )  (within ~1 ulp of np's pairwise
// f32 sum; bin partition of d = fp32(a - 2 dot) is invariant under ulp shifts)
// ---------------------------------------------------------------------------
__global__ __launch_bounds__(256)
void vq_rownorm(const float* __restrict__ Z, float* __restrict__ anorm) {
  const int lane = threadIdx.x & 63;
  const int wv   = threadIdx.x >> 6;
  const int row  = blockIdx.x * 4 + wv;
  const float4 z4 = *(const float4*)(Z + (size_t)row * DIMC + lane * 4);
  double s = (double)z4.x * z4.x + (double)z4.y * z4.y +
             (double)z4.z * z4.z + (double)z4.w * z4.w;
#pragma unroll
  for (int off = 32; off > 0; off >>= 1) s += __shfl_down(s, off);
  if (lane == 0) anorm[row] = (float)s;
}

// ---------------------------------------------------------------------------
// Kernel B: fp32 GEMM (dot = z.w) with fused argmin over d = fp32(a - 2*dot),
// tie -> lowest index (replicates np.float32 argmin-first semantics).
// Tile: 64 rows x 128 codewords, 128 threads, 8x8 per thread, full K per tile.
// ---------------------------------------------------------------------------
__global__ __launch_bounds__(128, 1)
void vq_gemm_argmin(const float* __restrict__ Z, const float* __restrict__ W,
                    const float* __restrict__ anorm, int* __restrict__ idxbuf) {
  __shared__ float As[32][64];    // [d][row]
  __shared__ float Bs[32][128];   // [d][col]

  const int t  = threadIdx.x;
  const int tx = t & 15;
  const int ty = t >> 4;
  const int m0 = blockIdx.x * 64;
  const int lr = t >> 3;          // 0..15
  const int dl = (t & 7) * 4;     // 0..28

  float arow[8];
#pragma unroll
  for (int rr = 0; rr < 8; ++rr)
    arow[rr] = anorm[m0 + (rr >> 2) * 32 + ty * 4 + (rr & 3)];

  float bd[8]; int bi[8];
#pragma unroll
  for (int rr = 0; rr < 8; ++rr) { bd[rr] = 3.4e38f; bi[rr] = 0x7fffffff; }

  float4 pa[4], pb[8];
  auto loadA = [&](int ch) {
#pragma unroll
    for (int i = 0; i < 4; ++i)
      pa[i] = *(const float4*)(Z + (size_t)(m0 + i * 16 + lr) * DIMC + ch * 32 + dl);
  };
  auto loadB = [&](int kt, int ch) {
#pragma unroll
    for (int i = 0; i < 8; ++i)
      pb[i] = *(const float4*)(W + (size_t)(kt * 128 + i * 16 + lr) * DIMC + ch * 32 + dl);
  };
  loadA(0); loadB(0, 0);

  for (int kt = 0; kt < 32; ++kt) {
    float acc[2][4][2][4];
#pragma unroll
    for (int im = 0; im < 2; ++im)
#pragma unroll
      for (int r = 0; r < 4; ++r)
#pragma unroll
        for (int jn = 0; jn < 2; ++jn)
#pragma unroll
          for (int cc = 0; cc < 4; ++cc) acc[im][r][jn][cc] = 0.0f;

    for (int ch = 0; ch < 8; ++ch) {
      __syncthreads();
#pragma unroll
      for (int i = 0; i < 4; ++i) {
        As[dl + 0][i * 16 + lr] = pa[i].x;
        As[dl + 1][i * 16 + lr] = pa[i].y;
        As[dl + 2][i * 16 + lr] = pa[i].z;
        As[dl + 3][i * 16 + lr] = pa[i].w;
      }
#pragma unroll
      for (int i = 0; i < 8; ++i) {
        Bs[dl + 0][i * 16 + lr] = pb[i].x;
        Bs[dl + 1][i * 16 + lr] = pb[i].y;
        Bs[dl + 2][i * 16 + lr] = pb[i].z;
        Bs[dl + 3][i * 16 + lr] = pb[i].w;
      }
      __syncthreads();
      const int nit = kt * 8 + ch + 1;
      if (nit < 256) { loadA(nit & 7); loadB(nit >> 3, nit & 7); }

#pragma unroll 4
      for (int d = 0; d < 32; ++d) {
        const float4 a0 = *(const float4*)&As[d][ty * 4];
        const float4 a1 = *(const float4*)&As[d][32 + ty * 4];
        const float4 b0 = *(const float4*)&Bs[d][tx * 4];
        const float4 b1 = *(const float4*)&Bs[d][64 + tx * 4];
        const float av[2][4] = {{a0.x, a0.y, a0.z, a0.w}, {a1.x, a1.y, a1.z, a1.w}};
        const float bv[2][4] = {{b0.x, b0.y, b0.z, b0.w}, {b1.x, b1.y, b1.z, b1.w}};
#pragma unroll
        for (int im = 0; im < 2; ++im)
#pragma unroll
          for (int r = 0; r < 4; ++r)
#pragma unroll
            for (int jn = 0; jn < 2; ++jn)
#pragma unroll
              for (int cc = 0; cc < 4; ++cc)
                acc[im][r][jn][cc] = fmaf(av[im][r], bv[jn][cc], acc[im][r][jn][cc]);
      }
    }

    // fused argmin epilogue for this 128-column tile
#pragma unroll
    for (int im = 0; im < 2; ++im)
#pragma unroll
      for (int r = 0; r < 4; ++r) {
        const int rr = im * 4 + r;
#pragma unroll
        for (int jn = 0; jn < 2; ++jn)
#pragma unroll
          for (int cc = 0; cc < 4; ++cc) {
            // d = fp32(a - 2*dot): 2*dot exact (pow2), one rounding — matches np
            const float d = arow[rr] - 2.0f * acc[im][r][jn][cc];
            const int idx = kt * 128 + jn * 64 + tx * 4 + cc;
            if (d < bd[rr] || (d == bd[rr] && idx < bi[rr])) { bd[rr] = d; bi[rr] = idx; }
          }
      }
  }

  // merge across the 16 lanes of each column group: lexicographic (d, idx)
#pragma unroll
  for (int rr = 0; rr < 8; ++rr) {
    float v = bd[rr]; int i = bi[rr];
#pragma unroll
    for (int mask = 1; mask < 16; mask <<= 1) {
      const float ov = __shfl_xor(v, mask, 16);
      const int   oi = __shfl_xor(i, mask, 16);
      if (ov < v || (ov == v && oi < i)) { v = ov; i = oi; }
    }
    if (tx == 0) {
      const int row = m0 + (rr >> 2) * 32 + ty * 4 + (rr & 3);
      idxbuf[row] = i;
    }
  }
}

// ---------------------------------------------------------------------------
// Kernel C: gather z_q, write indices, accumulate f64 loss + histogram.
// One wave per row, 4 rows per block.
// ---------------------------------------------------------------------------
__global__ __launch_bounds__(256)
void vq_select(const float* __restrict__ Z, const float* __restrict__ W,
               const int* __restrict__ idxbuf, float* __restrict__ zq_out,
               float* __restrict__ idx_out, double* __restrict__ loss_acc,
               int* __restrict__ hist) {
  __shared__ double sh[4];
  const int lane = threadIdx.x & 63;
  const int wv   = threadIdx.x >> 6;
  const int row  = blockIdx.x * 4 + wv;

  const int k = idxbuf[row];
  const float4 z4 = *(const float4*)(Z + (size_t)row * DIMC + lane * 4);
  const float4 w4 = *(const float4*)(W + (size_t)k   * DIMC + lane * 4);

  *(float4*)(zq_out + (size_t)row * DIMC + lane * 4) = w4;

  const double dx = (double)w4.x - (double)z4.x;
  const double dy = (double)w4.y - (double)z4.y;
  const double dz = (double)w4.z - (double)z4.z;
  const double dw = (double)w4.w - (double)z4.w;
  double l = dx * dx + dy * dy + dz * dz + dw * dw;
#pragma unroll
  for (int off = 32; off > 0; off >>= 1) l += __shfl_down(l, off);

  if (lane == 0) {
    sh[wv] = l;
    idx_out[row] = (float)k;
    atomicAdd(&hist[k], 1);
  }
  __syncthreads();
  if (threadIdx.x == 0) {
    unsafeAtomicAdd(loss_acc, sh[0] + sh[1] + sh[2] + sh[3]);
  }
}

// ---------------------------------------------------------------------------
// Kernel D: scalars — quant_loss = 1.25 * mean, perplexity (f64).
// ---------------------------------------------------------------------------
__global__ __launch_bounds__(64)
void vq_final(const double* __restrict__ loss_acc, const int* __restrict__ hist,
              float* __restrict__ scal) {
  const int lane = threadIdx.x;
  double H = 0.0;
  for (int k = lane; k < KC; k += 64) {
    const double p = (double)hist[k] / (double)NROWS;
    H -= p * log(p + 1e-10);
  }
#pragma unroll
  for (int off = 32; off > 0; off >>= 1) H += __shfl_down(H, off);
  if (lane == 0) {
    scal[0] = (float)(loss_acc[0] * 1.25 / ((double)NROWS * (double)DIMC));
    scal[1] = (float)exp(H);
  }
}

// ---------------------------------------------------------------------------
extern "C" void kernel_launch(void* const* d_in, const int* in_sizes, int n_in,
                              void* d_out, int out_size, void* d_ws, size_t ws_size,
                              hipStream_t stream) {
  const float* Z = (const float*)d_in[0];   // [32768,256]
  const float* W = (const float*)d_in[1];   // [4096,256]
  float* out = (float*)d_out;
  float* zq_out  = out;
  float* idx_out = out + (size_t)NROWS * DIMC;
  float* scal    = out + (size_t)NROWS * DIMC + NROWS;

  char* ws = (char*)d_ws;
  double* loss_acc = (double*)ws;                       // 8 B
  int*    hist     = (int*)(ws + 16);                   // 16 KB
  int*    idxbuf   = (int*)(ws + 16 + KC * 4);          // 128 KB
  float*  anorm    = (float*)(ws + 16 + KC * 4 + NROWS * 4); // 128 KB

  hipMemsetAsync(d_ws, 0, 16 + KC * 4, stream);
  vq_rownorm<<<NROWS / 4, 256, 0, stream>>>(Z, anorm);
  vq_gemm_argmin<<<NROWS / 64, 128, 0, stream>>>(Z, W, anorm, idxbuf);
  vq_select<<<NROWS / 4, 256, 0, stream>>>(Z, W, idxbuf, zq_out, idx_out, loss_acc, hist);
  vq_final<<<1, 64, 0, stream>>>(loss_acc, hist, scal);
}

// Round 3
// 758.994 us; speedup vs baseline: 2.3389x; 2.3389x over previous
//
#include <hip/hip_runtime.h>
#include <math.h>

constexpr int NROWS = 32768;   // B
constexpr int DIMC  = 256;     // D
constexpr int KC    = 4096;    // K

typedef __attribute__((ext_vector_type(8))) short short8;
typedef __attribute__((ext_vector_type(4))) float f32x4;

#define AS1 __attribute__((address_space(1)))
#define AS3 __attribute__((address_space(3)))

struct alignas(16) Part { float d1; int i1; float d2; int i2; };

__device__ __forceinline__ unsigned short f2bf(float x) {
  unsigned u = __float_as_uint(x);
  return (unsigned short)((u + 0x7fffu + ((u >> 16) & 1u)) >> 16);
}
__device__ __forceinline__ float bf2f(unsigned short b) {
  return __uint_as_float(((unsigned)b) << 16);
}

// ---------------------------------------------------------------------------
// Pre-pass: split fp32 matrix into h/l bf16 planes in the GEMM's tiled,
// swizzled HBM layout: [blk128][plane][kblk(8)][granule g=r*4+slot, 16B],
// where slot holds dim-octet s8 = slot ^ ((r>>1)&3)  (bank-conflict-free
// b128 reads AND linear order matches global_load_lds lane mapping).
// ---------------------------------------------------------------------------
__global__ __launch_bounds__(256)
void vq_split(const float* __restrict__ X, unsigned short* __restrict__ out) {
  const int blk = blockIdx.x >> 3;
  const int kb  = blockIdx.x & 7;
  const int t = threadIdx.x;
#pragma unroll
  for (int gi = 0; gi < 2; ++gi) {
    const int g = t + gi * 256;
    const int r = g >> 2, slot = g & 3;
    const int s8 = slot ^ ((r >> 1) & 3);
    const float* src = X + (size_t)(blk * 128 + r) * DIMC + kb * 32 + s8 * 8;
    short8 vh, vl;
#pragma unroll
    for (int j = 0; j < 8; ++j) {
      const float x = src[j];
      const unsigned short h = f2bf(x);
      const unsigned short l = f2bf(x - bf2f(h));
      vh[j] = (short)h; vl[j] = (short)l;
    }
    *(short8*)(out + ((size_t)(blk * 2 + 0) * 8 + kb) * 4096 + g * 8) = vh;
    *(short8*)(out + ((size_t)(blk * 2 + 1) * 8 + kb) * 4096 + g * 8) = vl;
  }
}

// ---------------------------------------------------------------------------
// anorm[row] = fp32(sum_f64 z^2)
// ---------------------------------------------------------------------------
__global__ __launch_bounds__(256)
void vq_rownorm(const float* __restrict__ Z, float* __restrict__ anorm) {
  const int lane = threadIdx.x & 63;
  const int wv   = threadIdx.x >> 6;
  const int row  = blockIdx.x * 4 + wv;
  const float4 z4 = *(const float4*)(Z + (size_t)row * DIMC + lane * 4);
  double s = (double)z4.x * z4.x + (double)z4.y * z4.y +
             (double)z4.z * z4.z + (double)z4.w * z4.w;
#pragma unroll
  for (int off = 32; off > 0; off >>= 1) s += __shfl_down(s, off);
  if (lane == 0) anorm[row] = (float)s;
}

// ---------------------------------------------------------------------------
// Main: split-bf16 MFMA GEMM (dot = hh + hl + lh) over 128x128 tiles,
// fused per-(row, colblock) top-2 of d = a - 2f*dot.
// ---------------------------------------------------------------------------
__global__ __launch_bounds__(256, 2)
void vq_mfma(const unsigned short* __restrict__ Zhl, const unsigned short* __restrict__ Whl,
             const float* __restrict__ anorm, Part* __restrict__ partial) {
  __shared__ char lds[32768];
  const int t = threadIdx.x, lane = t & 63, w = t >> 6;
  const int rb = blockIdx.x >> 5, cb = blockIdx.x & 31;
  const int q = lane >> 4, ml = lane & 15;
  const int wr = w >> 1, wc = w & 1;

  // wave w stages region w: 0=A-h, 1=A-l, 2=B-h, 3=B-l (8KB each)
  const unsigned short* src0 = (w < 2)
      ? Zhl + ((size_t)(rb * 2 + w) * 8) * 4096
      : Whl + ((size_t)(cb * 2 + (w - 2)) * 8) * 4096;
  char* ldsdst = lds + w * 8192;

  int aoff[4], boff[4];
#pragma unroll
  for (int i = 0; i < 4; ++i) {
    const int r = wr * 64 + i * 16 + ml;
    aoff[i] = (r * 4 + (q ^ ((r >> 1) & 3))) * 16;
    const int c = wc * 64 + i * 16 + ml;
    boff[i] = (c * 4 + (q ^ ((c >> 1) & 3))) * 16;
  }

  f32x4 acc[4][4];
#pragma unroll
  for (int i = 0; i < 4; ++i)
#pragma unroll
    for (int j = 0; j < 4; ++j) acc[i][j] = (f32x4){0.f, 0.f, 0.f, 0.f};

  for (int kb = 0; kb < 8; ++kb) {
    __syncthreads();
    const unsigned short* s = src0 + (size_t)kb * 4096 + lane * 8;
#pragma unroll
    for (int i = 0; i < 8; ++i)
      __builtin_amdgcn_global_load_lds((const AS1 void*)(s + i * 512),
                                       (AS3 void*)(ldsdst + i * 1024), 16, 0, 0);
    __syncthreads();
    short8 Ah[4], Al[4], Bh[4], Bl[4];
#pragma unroll
    for (int i = 0; i < 4; ++i) {
      Ah[i] = *(const short8*)(lds +         aoff[i]);
      Al[i] = *(const short8*)(lds +  8192 + aoff[i]);
      Bh[i] = *(const short8*)(lds + 16384 + boff[i]);
      Bl[i] = *(const short8*)(lds + 24576 + boff[i]);
    }
#pragma unroll
    for (int i = 0; i < 4; ++i)
#pragma unroll
      for (int j = 0; j < 4; ++j) {
        acc[i][j] = __builtin_amdgcn_mfma_f32_16x16x32_bf16(Al[i], Bh[j], acc[i][j], 0, 0, 0);
        acc[i][j] = __builtin_amdgcn_mfma_f32_16x16x32_bf16(Ah[i], Bl[j], acc[i][j], 0, 0, 0);
        acc[i][j] = __builtin_amdgcn_mfma_f32_16x16x32_bf16(Ah[i], Bh[j], acc[i][j], 0, 0, 0);
      }
  }

  // epilogue: top-2 per row over this block's 128 cols
  __syncthreads();
  float* pd1 = (float*)lds;            // [4 waves][64 rows]
  int*   pi1 = (int*)(lds + 1024);
  float* pd2 = (float*)(lds + 2048);
  const float INF = 3.4e38f;

#pragma unroll
  for (int i = 0; i < 4; ++i) {
#pragma unroll
    for (int r = 0; r < 4; ++r) {
      const int lr = i * 16 + q * 4 + r;                 // row within wave's 64
      const float am = anorm[rb * 128 + wr * 64 + lr];
      float d1m = INF, d2m = INF; int i1m = 0x7fffffff;
#pragma unroll
      for (int j = 0; j < 4; ++j) {
        const float d = am - 2.0f * acc[i][j][r];
        const int idx = cb * 128 + wc * 64 + j * 16 + ml;
        if (d < d1m || (d == d1m && idx < i1m)) { d2m = d1m; d1m = d; i1m = idx; }
        else d2m = fminf(d2m, d);
      }
#pragma unroll
      for (int mask = 1; mask < 16; mask <<= 1) {
        const float od1 = __shfl_xor(d1m, mask);
        const int   oi1 = __shfl_xor(i1m, mask);
        const float od2 = __shfl_xor(d2m, mask);
        if (od1 < d1m || (od1 == d1m && oi1 < i1m)) {
          d2m = fminf(d1m, od2); d1m = od1; i1m = oi1;
        } else d2m = fminf(d2m, od1);
      }
      if (ml == 0) { pd1[w * 64 + lr] = d1m; pi1[w * 64 + lr] = i1m; pd2[w * 64 + lr] = d2m; }
    }
  }
  __syncthreads();
  if (t < 128) {
    const int wrh = t >> 6, lr = t & 63;
    const int e0 = (wrh * 2 + 0) * 64 + lr, e1 = (wrh * 2 + 1) * 64 + lr;
    const float d1a = pd1[e0], d2a = pd2[e0]; const int i1a = pi1[e0];
    const float d1b = pd1[e1], d2b = pd2[e1]; const int i1b = pi1[e1];
    Part p;
    if (d1b < d1a || (d1b == d1a && i1b < i1a)) { p.d1 = d1b; p.i1 = i1b; p.d2 = fminf(d1a, d2b); }
    else                                        { p.d1 = d1a; p.i1 = i1a; p.d2 = fminf(d1b, d2a); }
    p.i2 = 0;
    const int row = rb * 128 + wrh * 64 + lr;
    partial[(size_t)row * 32 + cb] = p;
  }
}

// ---------------------------------------------------------------------------
// Merge 32 per-colblock partials per row; flag ambiguous rows (2nd-best
// within one fp32 bin width + slack of the best).
// ---------------------------------------------------------------------------
__global__ __launch_bounds__(256)
void vq_merge(const Part* __restrict__ partial, int* __restrict__ idxbuf,
              int* __restrict__ list, int* __restrict__ cnt) {
  const int row = blockIdx.x * 256 + threadIdx.x;
  float g1 = 3.4e38f, g2 = 3.4e38f; int gi = 0x7fffffff;
  for (int cbk = 0; cbk < 32; ++cbk) {
    const Part p = partial[(size_t)row * 32 + cbk];
    if (p.d1 < g1 || (p.d1 == g1 && p.i1 < gi)) {
      g2 = fminf(fminf(g2, g1), p.d2); g1 = p.d1; gi = p.i1;
    } else g2 = fminf(g2, p.d1);
  }
  idxbuf[row] = gi;
  if (g2 - g1 <= 3.3e-5f) { const int slot = atomicAdd(cnt, 1); list[slot] = row; }
}

// ---------------------------------------------------------------------------
// Rescue: full fp32-semantics rescore (all 4096 codes) for ambiguous rows.
// 8 rows per block; codebook streamed from L2.
// ---------------------------------------------------------------------------
__global__ __launch_bounds__(256)
void vq_rescue(const float* __restrict__ Z, const float* __restrict__ W,
               const float* __restrict__ anorm, const int* __restrict__ list,
               const int* __restrict__ cnt, int* __restrict__ idxbuf) {
  __shared__ float zs[8][256];
  __shared__ float as[8];
  __shared__ int   rowids[8];
  __shared__ float td[256 * 8];
  __shared__ int   ti[256 * 8];
  const int t = threadIdx.x;
  const int n = *cnt;
  for (int base = blockIdx.x * 8; base < n; base += gridDim.x * 8) {
    __syncthreads();
    const int nr = min(8, n - base);
    if (t < 8) {
      const int row = (t < nr) ? list[base + t] : list[base];
      rowids[t] = row; as[t] = anorm[row];
    }
    __syncthreads();
    for (int j = 0; j < 8; ++j) zs[j][t] = Z[(size_t)rowids[j] * 256 + t];
    __syncthreads();
    float bd[8]; int bi[8];
#pragma unroll
    for (int j = 0; j < 8; ++j) { bd[j] = 3.4e38f; bi[j] = 0x7fffffff; }
    for (int c = t; c < KC; c += 256) {
      float dots[8];
#pragma unroll
      for (int j = 0; j < 8; ++j) dots[j] = 0.f;
      for (int d0 = 0; d0 < 256; d0 += 4) {
        const float4 wv = *(const float4*)(W + (size_t)c * 256 + d0);
#pragma unroll
        for (int j = 0; j < 8; ++j) {
          dots[j] = fmaf(zs[j][d0],     wv.x, dots[j]);
          dots[j] = fmaf(zs[j][d0 + 1], wv.y, dots[j]);
          dots[j] = fmaf(zs[j][d0 + 2], wv.z, dots[j]);
          dots[j] = fmaf(zs[j][d0 + 3], wv.w, dots[j]);
        }
      }
#pragma unroll
      for (int j = 0; j < 8; ++j) {
        const float d = as[j] - 2.0f * dots[j];
        if (d < bd[j] || (d == bd[j] && c < bi[j])) { bd[j] = d; bi[j] = c; }
      }
    }
#pragma unroll
    for (int j = 0; j < 8; ++j) { td[t * 8 + j] = bd[j]; ti[t * 8 + j] = bi[j]; }
    __syncthreads();
    if (t < nr) {
      float g = 3.4e38f; int gix = 0x7fffffff;
      for (int u = 0; u < 256; ++u) {
        const float d = td[u * 8 + t]; const int ix = ti[u * 8 + t];
        if (d < g || (d == g && ix < gix)) { g = d; gix = ix; }
      }
      idxbuf[rowids[t]] = gix;
    }
  }
}

// ---------------------------------------------------------------------------
// Gather z_q, indices, f64 loss + histogram.
// ---------------------------------------------------------------------------
__global__ __launch_bounds__(256)
void vq_select(const float* __restrict__ Z, const float* __restrict__ W,
               const int* __restrict__ idxbuf, float* __restrict__ zq_out,
               float* __restrict__ idx_out, double* __restrict__ loss_acc,
               int* __restrict__ hist) {
  __shared__ double sh[4];
  const int lane = threadIdx.x & 63;
  const int wv   = threadIdx.x >> 6;
  const int row  = blockIdx.x * 4 + wv;

  const int k = idxbuf[row];
  const float4 z4 = *(const float4*)(Z + (size_t)row * DIMC + lane * 4);
  const float4 w4 = *(const float4*)(W + (size_t)k   * DIMC + lane * 4);
  *(float4*)(zq_out + (size_t)row * DIMC + lane * 4) = w4;

  const double dx = (double)w4.x - (double)z4.x;
  const double dy = (double)w4.y - (double)z4.y;
  const double dz = (double)w4.z - (double)z4.z;
  const double dw = (double)w4.w - (double)z4.w;
  double l = dx * dx + dy * dy + dz * dz + dw * dw;
#pragma unroll
  for (int off = 32; off > 0; off >>= 1) l += __shfl_down(l, off);

  if (lane == 0) { sh[wv] = l; idx_out[row] = (float)k; atomicAdd(&hist[k], 1); }
  __syncthreads();
  if (threadIdx.x == 0) unsafeAtomicAdd(loss_acc, sh[0] + sh[1] + sh[2] + sh[3]);
}

__global__ __launch_bounds__(64)
void vq_final(const double* __restrict__ loss_acc, const int* __restrict__ hist,
              float* __restrict__ scal) {
  const int lane = threadIdx.x;
  double H = 0.0;
  for (int k = lane; k < KC; k += 64) {
    const double p = (double)hist[k] / (double)NROWS;
    H -= p * log(p + 1e-10);
  }
#pragma unroll
  for (int off = 32; off > 0; off >>= 1) H += __shfl_down(H, off);
  if (lane == 0) {
    scal[0] = (float)(loss_acc[0] * 1.25 / ((double)NROWS * (double)DIMC));
    scal[1] = (float)exp(H);
  }
}

// ---------------------------------------------------------------------------
extern "C" void kernel_launch(void* const* d_in, const int* in_sizes, int n_in,
                              void* d_out, int out_size, void* d_ws, size_t ws_size,
                              hipStream_t stream) {
  const float* Z = (const float*)d_in[0];
  const float* W = (const float*)d_in[1];
  float* out = (float*)d_out;
  float* zq_out  = out;
  float* idx_out = out + (size_t)NROWS * DIMC;
  float* scal    = idx_out + NROWS;

  char* ws = (char*)d_ws;
  double* loss_acc   = (double*)ws;                       // 8 B @0
  int*    cnt        = (int*)(ws + 8);
  int*    hist       = (int*)(ws + 1024);                 // 16 KB
  int*    idxbuf     = (int*)(ws + 32768);                // 128 KB
  float*  anorm      = (float*)(ws + 163840);             // 128 KB
  int*    list       = (int*)(ws + 294912);               // 128 KB
  Part*   partial    = (Part*)(ws + 1048576);             // 16 MB
  unsigned short* Zhl = (unsigned short*)(ws + 20971520); // 32 MB
  unsigned short* Whl = (unsigned short*)(ws + 54525952); // 4 MB (end 56 MB)

  hipMemsetAsync(ws, 0, 17408, stream);                   // loss + cnt + hist
  vq_split<<<2048, 256, 0, stream>>>(Z, Zhl);
  vq_split<<<256, 256, 0, stream>>>(W, Whl);
  vq_rownorm<<<NROWS / 4, 256, 0, stream>>>(Z, anorm);
  vq_mfma<<<8192, 256, 0, stream>>>(Zhl, Whl, anorm, partial);
  vq_merge<<<128, 256, 0, stream>>>(partial, idxbuf, list, cnt);
  vq_rescue<<<512, 256, 0, stream>>>(Z, W, anorm, list, cnt, idxbuf);
  vq_select<<<NROWS / 4, 256, 0, stream>>>(Z, W, idxbuf, zq_out, idx_out, loss_acc, hist);
  vq_final<<<1, 64, 0, stream>>>(loss_acc, hist, scal);
}

// Round 4
// 557.042 us; speedup vs baseline: 3.1869x; 1.3625x over previous
//
#include <hip/hip_runtime.h>
#include <math.h>

constexpr int NROWS = 32768;   // B
constexpr int DIMC  = 256;     // D
constexpr int KC    = 4096;    // K

typedef __attribute__((ext_vector_type(8))) short short8;
typedef __attribute__((ext_vector_type(4))) float f32x4;

#define AS1 __attribute__((address_space(1)))
#define AS3 __attribute__((address_space(3)))

struct alignas(16) Part { float d1; int i1; float d2; int i2; };
struct alignas(8)  Pair { float d; int i; };

__device__ __forceinline__ unsigned short f2bf(float x) {
  unsigned u = __float_as_uint(x);
  return (unsigned short)((u + 0x7fffu + ((u >> 16) & 1u)) >> 16);
}
__device__ __forceinline__ float bf2f(unsigned short b) {
  return __uint_as_float(((unsigned)b) << 16);
}

// ---------------------------------------------------------------------------
// Pre-pass: split fp32 matrix into h/l bf16 planes in the GEMM's tiled,
// swizzled HBM layout (see round-3 notes; layout validated by passing run).
// ---------------------------------------------------------------------------
__global__ __launch_bounds__(256)
void vq_split(const float* __restrict__ X, unsigned short* __restrict__ out) {
  const int blk = blockIdx.x >> 3;
  const int kb  = blockIdx.x & 7;
  const int t = threadIdx.x;
#pragma unroll
  for (int gi = 0; gi < 2; ++gi) {
    const int g = t + gi * 256;
    const int r = g >> 2, slot = g & 3;
    const int s8 = slot ^ ((r >> 1) & 3);
    const float* src = X + (size_t)(blk * 128 + r) * DIMC + kb * 32 + s8 * 8;
    short8 vh, vl;
#pragma unroll
    for (int j = 0; j < 8; ++j) {
      const float x = src[j];
      const unsigned short h = f2bf(x);
      const unsigned short l = f2bf(x - bf2f(h));
      vh[j] = (short)h; vl[j] = (short)l;
    }
    *(short8*)(out + ((size_t)(blk * 2 + 0) * 8 + kb) * 4096 + g * 8) = vh;
    *(short8*)(out + ((size_t)(blk * 2 + 1) * 8 + kb) * 4096 + g * 8) = vl;
  }
}

// ---------------------------------------------------------------------------
__global__ __launch_bounds__(256)
void vq_rownorm(const float* __restrict__ Z, float* __restrict__ anorm) {
  const int lane = threadIdx.x & 63;
  const int wv   = threadIdx.x >> 6;
  const int row  = blockIdx.x * 4 + wv;
  const float4 z4 = *(const float4*)(Z + (size_t)row * DIMC + lane * 4);
  double s = (double)z4.x * z4.x + (double)z4.y * z4.y +
             (double)z4.z * z4.z + (double)z4.w * z4.w;
#pragma unroll
  for (int off = 32; off > 0; off >>= 1) s += __shfl_down(s, off);
  if (lane == 0) anorm[row] = (float)s;
}

// ---------------------------------------------------------------------------
// Main: split-bf16 MFMA GEMM (dot = hh + hl + lh), 128x128 tiles,
// fused per-(row, colblock) top-2 of d = a - 2f*dot.   (unchanged, validated)
// ---------------------------------------------------------------------------
__global__ __launch_bounds__(256, 2)
void vq_mfma(const unsigned short* __restrict__ Zhl, const unsigned short* __restrict__ Whl,
             const float* __restrict__ anorm, Part* __restrict__ partial) {
  __shared__ char lds[32768];
  const int t = threadIdx.x, lane = t & 63, w = t >> 6;
  const int rb = blockIdx.x >> 5, cb = blockIdx.x & 31;
  const int q = lane >> 4, ml = lane & 15;
  const int wr = w >> 1, wc = w & 1;

  const unsigned short* src0 = (w < 2)
      ? Zhl + ((size_t)(rb * 2 + w) * 8) * 4096
      : Whl + ((size_t)(cb * 2 + (w - 2)) * 8) * 4096;
  char* ldsdst = lds + w * 8192;

  int aoff[4], boff[4];
#pragma unroll
  for (int i = 0; i < 4; ++i) {
    const int r = wr * 64 + i * 16 + ml;
    aoff[i] = (r * 4 + (q ^ ((r >> 1) & 3))) * 16;
    const int c = wc * 64 + i * 16 + ml;
    boff[i] = (c * 4 + (q ^ ((c >> 1) & 3))) * 16;
  }

  f32x4 acc[4][4];
#pragma unroll
  for (int i = 0; i < 4; ++i)
#pragma unroll
    for (int j = 0; j < 4; ++j) acc[i][j] = (f32x4){0.f, 0.f, 0.f, 0.f};

  for (int kb = 0; kb < 8; ++kb) {
    __syncthreads();
    const unsigned short* s = src0 + (size_t)kb * 4096 + lane * 8;
#pragma unroll
    for (int i = 0; i < 8; ++i)
      __builtin_amdgcn_global_load_lds((const AS1 void*)(s + i * 512),
                                       (AS3 void*)(ldsdst + i * 1024), 16, 0, 0);
    __syncthreads();
    short8 Ah[4], Al[4], Bh[4], Bl[4];
#pragma unroll
    for (int i = 0; i < 4; ++i) {
      Ah[i] = *(const short8*)(lds +         aoff[i]);
      Al[i] = *(const short8*)(lds +  8192 + aoff[i]);
      Bh[i] = *(const short8*)(lds + 16384 + boff[i]);
      Bl[i] = *(const short8*)(lds + 24576 + boff[i]);
    }
#pragma unroll
    for (int i = 0; i < 4; ++i)
#pragma unroll
      for (int j = 0; j < 4; ++j) {
        acc[i][j] = __builtin_amdgcn_mfma_f32_16x16x32_bf16(Al[i], Bh[j], acc[i][j], 0, 0, 0);
        acc[i][j] = __builtin_amdgcn_mfma_f32_16x16x32_bf16(Ah[i], Bl[j], acc[i][j], 0, 0, 0);
        acc[i][j] = __builtin_amdgcn_mfma_f32_16x16x32_bf16(Ah[i], Bh[j], acc[i][j], 0, 0, 0);
      }
  }

  __syncthreads();
  float* pd1 = (float*)lds;
  int*   pi1 = (int*)(lds + 1024);
  float* pd2 = (float*)(lds + 2048);
  const float INF = 3.4e38f;

#pragma unroll
  for (int i = 0; i < 4; ++i) {
#pragma unroll
    for (int r = 0; r < 4; ++r) {
      const int lr = i * 16 + q * 4 + r;
      const float am = anorm[rb * 128 + wr * 64 + lr];
      float d1m = INF, d2m = INF; int i1m = 0x7fffffff;
#pragma unroll
      for (int j = 0; j < 4; ++j) {
        const float d = am - 2.0f * acc[i][j][r];
        const int idx = cb * 128 + wc * 64 + j * 16 + ml;
        if (d < d1m || (d == d1m && idx < i1m)) { d2m = d1m; d1m = d; i1m = idx; }
        else d2m = fminf(d2m, d);
      }
#pragma unroll
      for (int mask = 1; mask < 16; mask <<= 1) {
        const float od1 = __shfl_xor(d1m, mask);
        const int   oi1 = __shfl_xor(i1m, mask);
        const float od2 = __shfl_xor(d2m, mask);
        if (od1 < d1m || (od1 == d1m && oi1 < i1m)) {
          d2m = fminf(d1m, od2); d1m = od1; i1m = oi1;
        } else d2m = fminf(d2m, od1);
      }
      if (ml == 0) { pd1[w * 64 + lr] = d1m; pi1[w * 64 + lr] = i1m; pd2[w * 64 + lr] = d2m; }
    }
  }
  __syncthreads();
  if (t < 128) {
    const int wrh = t >> 6, lr = t & 63;
    const int e0 = (wrh * 2 + 0) * 64 + lr, e1 = (wrh * 2 + 1) * 64 + lr;
    const float d1a = pd1[e0], d2a = pd2[e0]; const int i1a = pi1[e0];
    const float d1b = pd1[e1], d2b = pd2[e1]; const int i1b = pi1[e1];
    Part p;
    if (d1b < d1a || (d1b == d1a && i1b < i1a)) { p.d1 = d1b; p.i1 = i1b; p.d2 = fminf(d1a, d2b); }
    else                                        { p.d1 = d1a; p.i1 = i1a; p.d2 = fminf(d1b, d2a); }
    p.i2 = 0;
    const int row = rb * 128 + wrh * 64 + lr;
    partial[(size_t)row * 32 + cb] = p;
  }
}

// ---------------------------------------------------------------------------
// Merge partials; flag rows whose top-2 gap is within the np fp32 bin width
// (ulp of d: 1.53e-5 below 256, 3.05e-5 above) + margin.
// ---------------------------------------------------------------------------
__global__ __launch_bounds__(256)
void vq_merge(const Part* __restrict__ partial, int* __restrict__ idxbuf,
              int* __restrict__ list, int* __restrict__ cnt) {
  const int row = blockIdx.x * 256 + threadIdx.x;
  float g1 = 3.4e38f, g2 = 3.4e38f; int gi = 0x7fffffff;
  for (int cbk = 0; cbk < 32; ++cbk) {
    const Part p = partial[(size_t)row * 32 + cbk];
    if (p.d1 < g1 || (p.d1 == g1 && p.i1 < gi)) {
      g2 = fminf(fminf(g2, g1), p.d2); g1 = p.d1; gi = p.i1;
    } else g2 = fminf(g2, p.d1);
  }
  idxbuf[row] = gi;
  const float binw = (g1 >= 255.9f) ? 3.06e-5f : 1.53e-5f;
  if (g2 - g1 <= binw + 1.0e-6f) { const int slot = atomicAdd(cnt, 1); list[slot] = row; }
}

// ---------------------------------------------------------------------------
// Rescue v2: fp32-semantics rescore, decomposed as 8 rows x 512-code chunk
// per block (grid 2048 = 256 rowgroups x 8 chunks). Per-code computation is
// identical to the round-3-validated rescue (ascending-dim fmaf chain,
// d = a - 2f*dot, tie -> lower index); partials merged by vq_merge2.
// ---------------------------------------------------------------------------
__global__ __launch_bounds__(256)
void vq_rescue(const float* __restrict__ Z, const float* __restrict__ W,
               const float* __restrict__ anorm, const int* __restrict__ list,
               const int* __restrict__ cnt, Pair* __restrict__ part2) {
  __shared__ float zs[8][256];
  __shared__ float as[8];
  __shared__ int   rowids[8];
  __shared__ float td[256 * 8];
  __shared__ int   ti[256 * 8];
  const int t = threadIdx.x;
  const int n = *cnt;
  const int chunk = blockIdx.x & 7;           // 512-code chunk
  for (int g = blockIdx.x >> 3; g * 8 < n; g += 256) {
    __syncthreads();
    const int base = g * 8;
    const int nr = min(8, n - base);
    if (t < 8) {
      const int row = list[base + min(t, nr - 1)];
      rowids[t] = row; as[t] = anorm[row];
    }
    __syncthreads();
    for (int j = 0; j < 8; ++j) zs[j][t] = Z[(size_t)rowids[j] * 256 + t];
    __syncthreads();
    float bd[8]; int bi[8];
#pragma unroll
    for (int j = 0; j < 8; ++j) { bd[j] = 3.4e38f; bi[j] = 0x7fffffff; }
#pragma unroll
    for (int u = 0; u < 2; ++u) {
      const int c = chunk * 512 + u * 256 + t;
      float dots[8];
#pragma unroll
      for (int j = 0; j < 8; ++j) dots[j] = 0.f;
      for (int d0 = 0; d0 < 256; d0 += 4) {
        const float4 wv = *(const float4*)(W + (size_t)c * 256 + d0);
#pragma unroll
        for (int j = 0; j < 8; ++j) {
          dots[j] = fmaf(zs[j][d0],     wv.x, dots[j]);
          dots[j] = fmaf(zs[j][d0 + 1], wv.y, dots[j]);
          dots[j] = fmaf(zs[j][d0 + 2], wv.z, dots[j]);
          dots[j] = fmaf(zs[j][d0 + 3], wv.w, dots[j]);
        }
      }
#pragma unroll
      for (int j = 0; j < 8; ++j) {
        const float d = as[j] - 2.0f * dots[j];
        if (d < bd[j] || (d == bd[j] && c < bi[j])) { bd[j] = d; bi[j] = c; }
      }
    }
#pragma unroll
    for (int j = 0; j < 8; ++j) { td[t * 8 + j] = bd[j]; ti[t * 8 + j] = bi[j]; }
    __syncthreads();
    if (t < nr) {
      float gd = 3.4e38f; int gix = 0x7fffffff;
      for (int u = 0; u < 256; ++u) {
        const float d = td[u * 8 + t]; const int ix = ti[u * 8 + t];
        if (d < gd || (d == gd && ix < gix)) { gd = d; gix = ix; }
      }
      Pair p; p.d = gd; p.i = gix;
      part2[(size_t)(base + t) * 8 + chunk] = p;
    }
  }
}

// ---------------------------------------------------------------------------
// Merge the 8 per-chunk partials of each rescued row.
// ---------------------------------------------------------------------------
__global__ __launch_bounds__(256)
void vq_merge2(const Pair* __restrict__ part2, const int* __restrict__ list,
               const int* __restrict__ cnt, int* __restrict__ idxbuf) {
  const int n = *cnt;
  for (int i = blockIdx.x * 256 + threadIdx.x; i < n; i += gridDim.x * 256) {
    float g = 3.4e38f; int gi = 0x7fffffff;
#pragma unroll
    for (int c = 0; c < 8; ++c) {
      const Pair p = part2[(size_t)i * 8 + c];
      if (p.d < g || (p.d == g && p.i < gi)) { g = p.d; gi = p.i; }
    }
    idxbuf[list[i]] = gi;
  }
}

// ---------------------------------------------------------------------------
__global__ __launch_bounds__(256)
void vq_select(const float* __restrict__ Z, const float* __restrict__ W,
               const int* __restrict__ idxbuf, float* __restrict__ zq_out,
               float* __restrict__ idx_out, double* __restrict__ loss_acc,
               int* __restrict__ hist) {
  __shared__ double sh[4];
  const int lane = threadIdx.x & 63;
  const int wv   = threadIdx.x >> 6;
  const int row  = blockIdx.x * 4 + wv;

  const int k = idxbuf[row];
  const float4 z4 = *(const float4*)(Z + (size_t)row * DIMC + lane * 4);
  const float4 w4 = *(const float4*)(W + (size_t)k   * DIMC + lane * 4);
  *(float4*)(zq_out + (size_t)row * DIMC + lane * 4) = w4;

  const double dx = (double)w4.x - (double)z4.x;
  const double dy = (double)w4.y - (double)z4.y;
  const double dz = (double)w4.z - (double)z4.z;
  const double dw = (double)w4.w - (double)z4.w;
  double l = dx * dx + dy * dy + dz * dz + dw * dw;
#pragma unroll
  for (int off = 32; off > 0; off >>= 1) l += __shfl_down(l, off);

  if (lane == 0) { sh[wv] = l; idx_out[row] = (float)k; atomicAdd(&hist[k], 1); }
  __syncthreads();
  if (threadIdx.x == 0) unsafeAtomicAdd(loss_acc, sh[0] + sh[1] + sh[2] + sh[3]);
}

__global__ __launch_bounds__(64)
void vq_final(const double* __restrict__ loss_acc, const int* __restrict__ hist,
              float* __restrict__ scal) {
  const int lane = threadIdx.x;
  double H = 0.0;
  for (int k = lane; k < KC; k += 64) {
    const double p = (double)hist[k] / (double)NROWS;
    H -= p * log(p + 1e-10);
  }
#pragma unroll
  for (int off = 32; off > 0; off >>= 1) H += __shfl_down(H, off);
  if (lane == 0) {
    scal[0] = (float)(loss_acc[0] * 1.25 / ((double)NROWS * (double)DIMC));
    scal[1] = (float)exp(H);
  }
}

// ---------------------------------------------------------------------------
extern "C" void kernel_launch(void* const* d_in, const int* in_sizes, int n_in,
                              void* d_out, int out_size, void* d_ws, size_t ws_size,
                              hipStream_t stream) {
  const float* Z = (const float*)d_in[0];
  const float* W = (const float*)d_in[1];
  float* out = (float*)d_out;
  float* zq_out  = out;
  float* idx_out = out + (size_t)NROWS * DIMC;
  float* scal    = idx_out + NROWS;

  char* ws = (char*)d_ws;
  double* loss_acc   = (double*)ws;                       // 8 B @0
  int*    cnt        = (int*)(ws + 8);
  int*    hist       = (int*)(ws + 1024);                 // 16 KB
  int*    idxbuf     = (int*)(ws + 32768);                // 128 KB
  float*  anorm      = (float*)(ws + 163840);             // 128 KB
  int*    list       = (int*)(ws + 294912);               // 128 KB
  Part*   partial    = (Part*)(ws + 1048576);             // 16 MB @ 1 MB
  Pair*   part2      = (Pair*)(ws + 17825792);            // 2 MB  @ 17 MB
  unsigned short* Zhl = (unsigned short*)(ws + 20971520); // 32 MB @ 20 MB
  unsigned short* Whl = (unsigned short*)(ws + 54525952); // 4 MB

  hipMemsetAsync(ws, 0, 17408, stream);                   // loss + cnt + hist
  vq_split<<<2048, 256, 0, stream>>>(Z, Zhl);
  vq_split<<<256, 256, 0, stream>>>(W, Whl);
  vq_rownorm<<<NROWS / 4, 256, 0, stream>>>(Z, anorm);
  vq_mfma<<<8192, 256, 0, stream>>>(Zhl, Whl, anorm, partial);
  vq_merge<<<128, 256, 0, stream>>>(partial, idxbuf, list, cnt);
  vq_rescue<<<2048, 256, 0, stream>>>(Z, W, anorm, list, cnt, part2);
  vq_merge2<<<32, 256, 0, stream>>>(part2, list, cnt, idxbuf);
  vq_select<<<NROWS / 4, 256, 0, stream>>>(Z, W, idxbuf, zq_out, idx_out, loss_acc, hist);
  vq_final<<<1, 64, 0, stream>>>(loss_acc, hist, scal);
}